// Round 1
// baseline (122.001 us; speedup 1.0000x reference)
//
#include <hip/hip_runtime.h>
#include <math.h>

#define NN 1024
#define IN_F 256
#define OUT_F 128
#define NHEADS 4
#define NHF 32

// K1: g_l = h @ Wl^T, g_r = h @ Wr^T, written as [head][j][f] fp32.
// Block b handles rows j0..j0+3; thread c in [0,256): c<128 -> Wl col c, else Wr col c-128.
__global__ void __launch_bounds__(256) glr_gemm(const float* __restrict__ hmat,
                                                const float* __restrict__ Wl,
                                                const float* __restrict__ Wr,
                                                float* __restrict__ glh,
                                                float* __restrict__ grh) {
    __shared__ float hsh[4][IN_F];
    const int tid = threadIdx.x;
    const int j0  = blockIdx.x * 4;
    for (int t = tid; t < 4 * IN_F; t += 256) {
        hsh[t >> 8][t & 255] = hmat[j0 * IN_F + t];   // rows are contiguous
    }
    __syncthreads();
    const int c = tid;
    const float* __restrict__ Wrow = (c < OUT_F) ? (Wl + c * IN_F) : (Wr + (c - OUT_F) * IN_F);
    float acc0 = 0.f, acc1 = 0.f, acc2 = 0.f, acc3 = 0.f;
#pragma unroll 4
    for (int k = 0; k < IN_F; k += 4) {
        const float4 w  = *(const float4*)(Wrow + k);
        const float4 a0 = *(const float4*)&hsh[0][k];
        const float4 a1 = *(const float4*)&hsh[1][k];
        const float4 a2 = *(const float4*)&hsh[2][k];
        const float4 a3 = *(const float4*)&hsh[3][k];
        acc0 = fmaf(a0.x, w.x, fmaf(a0.y, w.y, fmaf(a0.z, w.z, fmaf(a0.w, w.w, acc0))));
        acc1 = fmaf(a1.x, w.x, fmaf(a1.y, w.y, fmaf(a1.z, w.z, fmaf(a1.w, w.w, acc1))));
        acc2 = fmaf(a2.x, w.x, fmaf(a2.y, w.y, fmaf(a2.z, w.z, fmaf(a2.w, w.w, acc2))));
        acc3 = fmaf(a3.x, w.x, fmaf(a3.y, w.y, fmaf(a3.z, w.z, fmaf(a3.w, w.w, acc3))));
    }
    const int which = (c >= OUT_F);
    const int cc = which ? (c - OUT_F) : c;
    const int hh = cc >> 5, f = cc & 31;
    float* __restrict__ dst = which ? grh : glh;
    dst[(hh * NN + j0 + 0) * NHF + f] = acc0;
    dst[(hh * NN + j0 + 1) * NHF + f] = acc1;
    dst[(hh * NN + j0 + 2) * NHF + f] = acc2;
    dst[(hh * NN + j0 + 3) * NHF + f] = acc3;
}

// K2: one block per (i-tile of 8, head). Phase A: e[i,j] with lanes<->j, e in LDS.
// Phase B: softmax (block-reduced max, exp, block-reduced sum).
// Phase C: o[i,f] = sum_j p[i,j]*g_r[j,h,f], thread <-> (ii,f), then /l + ELU.
__global__ void __launch_bounds__(256) gat_main(const float* __restrict__ glh,
                                                const float* __restrict__ grh,
                                                const int* __restrict__ adj,
                                                const float* __restrict__ attn_w,
                                                float* __restrict__ out) {
    const int hh  = blockIdx.y;
    const int i0  = blockIdx.x * 8;
    const int tid = threadIdx.x;

    __shared__ float e_buf[8][1028];   // stride 1028 floats: 16B-aligned rows, conflict-free
    __shared__ float gr_i[8][32];
    __shared__ float wred[8][4];
    __shared__ float m_sh[8];
    __shared__ float l_sh[8];

    {
        const int ii = tid >> 5, f = tid & 31;
        gr_i[ii][f] = grh[(hh * NN + i0 + ii) * NHF + f];
    }
    float w06[NHF];
#pragma unroll
    for (int f = 0; f < NHF; ++f) w06[f] = 0.6f * attn_w[f];
    const float C23 = 0x1.555556p-1f;  // 2/3: lrelu(s)*w == 0.6w*(s + (2/3)|s|)
    __syncthreads();

    float mpart[8];
#pragma unroll
    for (int ii = 0; ii < 8; ++ii) mpart[ii] = -1e30f;

    for (int c = 0; c < 4; ++c) {
        const int j = (c << 8) + tid;
        float gl_r[NHF];
#pragma unroll
        for (int f4 = 0; f4 < 8; ++f4) {
            const float4 v = *(const float4*)(glh + (hh * NN + j) * NHF + (f4 << 2));
            gl_r[f4 * 4 + 0] = v.x; gl_r[f4 * 4 + 1] = v.y;
            gl_r[f4 * 4 + 2] = v.z; gl_r[f4 * 4 + 3] = v.w;
        }
        int adjv[8];
#pragma unroll
        for (int ii = 0; ii < 8; ++ii) adjv[ii] = adj[(i0 + ii) * NN + j];
#pragma unroll
        for (int ii = 0; ii < 8; ++ii) {
            float e = 0.f;
#pragma unroll
            for (int f4 = 0; f4 < 8; ++f4) {
                const float4 g = *(const float4*)&gr_i[ii][f4 << 2];
                float s;
                s = gl_r[f4 * 4 + 0] + g.x; e = fmaf(fmaf(fabsf(s), C23, s), w06[f4 * 4 + 0], e);
                s = gl_r[f4 * 4 + 1] + g.y; e = fmaf(fmaf(fabsf(s), C23, s), w06[f4 * 4 + 1], e);
                s = gl_r[f4 * 4 + 2] + g.z; e = fmaf(fmaf(fabsf(s), C23, s), w06[f4 * 4 + 2], e);
                s = gl_r[f4 * 4 + 3] + g.w; e = fmaf(fmaf(fabsf(s), C23, s), w06[f4 * 4 + 3], e);
            }
            e = adjv[ii] ? e : -1e30f;
            e_buf[ii][j] = e;
            mpart[ii] = fmaxf(mpart[ii], e);
        }
    }

    // block-reduce max per ii
#pragma unroll
    for (int ii = 0; ii < 8; ++ii) {
        float v = mpart[ii];
#pragma unroll
        for (int d = 32; d > 0; d >>= 1) v = fmaxf(v, __shfl_xor(v, d));
        if ((tid & 63) == 0) wred[ii][tid >> 6] = v;
    }
    __syncthreads();
    if (tid < 8) m_sh[tid] = fmaxf(fmaxf(wred[tid][0], wred[tid][1]),
                                   fmaxf(wred[tid][2], wred[tid][3]));
    __syncthreads();

    // exp pass + sum
    float lpart[8];
#pragma unroll
    for (int ii = 0; ii < 8; ++ii) lpart[ii] = 0.f;
    for (int c = 0; c < 4; ++c) {
        const int j = (c << 8) + tid;
#pragma unroll
        for (int ii = 0; ii < 8; ++ii) {
            const float p = __expf(e_buf[ii][j] - m_sh[ii]);
            e_buf[ii][j] = p;
            lpart[ii] += p;
        }
    }
#pragma unroll
    for (int ii = 0; ii < 8; ++ii) {
        float v = lpart[ii];
#pragma unroll
        for (int d = 32; d > 0; d >>= 1) v += __shfl_xor(v, d);
        if ((tid & 63) == 0) wred[ii][tid >> 6] = v;
    }
    __syncthreads();
    if (tid < 8) l_sh[tid] = wred[tid][0] + wred[tid][1] + wred[tid][2] + wred[tid][3];
    __syncthreads();

    // Phase C: aggregation. thread <-> (ii, f); per j the wave reads one 128B g_r segment.
    const int ii = tid >> 5, f = tid & 31;
    const float* __restrict__ grb = grh + hh * NN * NHF + f;
    float o0 = 0.f, o1 = 0.f, o2 = 0.f, o3 = 0.f;
    for (int j = 0; j < NN; j += 4) {
        const float4 p4 = *(const float4*)&e_buf[ii][j];
        const float g0 = grb[(j + 0) * NHF];
        const float g1 = grb[(j + 1) * NHF];
        const float g2 = grb[(j + 2) * NHF];
        const float g3 = grb[(j + 3) * NHF];
        o0 = fmaf(p4.x, g0, o0);
        o1 = fmaf(p4.y, g1, o1);
        o2 = fmaf(p4.z, g2, o2);
        o3 = fmaf(p4.w, g3, o3);
    }
    float o = (o0 + o1) + (o2 + o3);
    o /= l_sh[ii];
    const float r = (o > 0.f) ? o : (__expf(o) - 1.f);
    out[(i0 + ii) * OUT_F + hh * NHF + f] = r;
}

extern "C" void kernel_launch(void* const* d_in, const int* in_sizes, int n_in,
                              void* d_out, int out_size, void* d_ws, size_t ws_size,
                              hipStream_t stream) {
    const float* hmat = (const float*)d_in[0];
    const int*   adj  = (const int*)d_in[1];
    const float* Wl   = (const float*)d_in[2];
    const float* Wr   = (const float*)d_in[3];
    const float* aw   = (const float*)d_in[4];
    float* o          = (float*)d_out;

    float* glh = (float*)d_ws;                 // [4][1024][32]
    float* grh = glh + NHEADS * NN * NHF;      // [4][1024][32]

    glr_gemm<<<dim3(NN / 4), dim3(256), 0, stream>>>(hmat, Wl, Wr, glh, grh);
    gat_main<<<dim3(NN / 8, NHEADS), dim3(256), 0, stream>>>(glh, grh, adj, aw, o);
}

// Round 2
// 108.936 us; speedup vs baseline: 1.1199x; 1.1199x over previous
//
#include <hip/hip_runtime.h>
#include <math.h>

#define NN 1024
#define IN_F 256
#define OUT_F 128
#define NHEADS 4
#define NHF 32

// K1: g_l = h @ Wl^T, g_r = h @ Wr^T  -> [head][j][f] fp32, plus
// alpha[h][j] = dot(attn_w, g_l[j,h,:]), beta[h][i] = dot(attn_w, g_r[i,h,:]).
// 512 blocks x 256 threads, 2 rows per block (2 blocks/CU, 8 waves/CU).
__global__ void __launch_bounds__(256) glr_gemm(const float* __restrict__ hmat,
                                                const float* __restrict__ Wl,
                                                const float* __restrict__ Wr,
                                                const float* __restrict__ attn_w,
                                                float* __restrict__ glh,
                                                float* __restrict__ grh,
                                                float* __restrict__ alpha,
                                                float* __restrict__ beta) {
    __shared__ float hsh[2][IN_F];
    const int tid = threadIdx.x;
    const int j0  = blockIdx.x * 2;
    for (int t = tid; t < 2 * IN_F; t += 256) {
        hsh[t >> 8][t & 255] = hmat[j0 * IN_F + t];
    }
    __syncthreads();
    const int c = tid;
    const float* __restrict__ Wrow = (c < OUT_F) ? (Wl + c * IN_F) : (Wr + (c - OUT_F) * IN_F);
    float a0 = 0.f, a1 = 0.f;
#pragma unroll 8
    for (int k = 0; k < IN_F; k += 4) {
        const float4 w  = *(const float4*)(Wrow + k);
        const float4 x0 = *(const float4*)&hsh[0][k];
        const float4 x1 = *(const float4*)&hsh[1][k];
        a0 = fmaf(x0.x, w.x, fmaf(x0.y, w.y, fmaf(x0.z, w.z, fmaf(x0.w, w.w, a0))));
        a1 = fmaf(x1.x, w.x, fmaf(x1.y, w.y, fmaf(x1.z, w.z, fmaf(x1.w, w.w, a1))));
    }
    const int f = c & 31;
    // weighted lane-reduce over the 32-lane f-group for alpha/beta
    const float wf = attn_w[f];
    float d0 = a0 * wf, d1 = a1 * wf;
#pragma unroll
    for (int d = 16; d > 0; d >>= 1) {
        d0 += __shfl_xor(d0, d);
        d1 += __shfl_xor(d1, d);
    }
    const int which = (c >= OUT_F);
    const int cc = which ? (c - OUT_F) : c;
    const int hh = cc >> 5;
    float* __restrict__ dst = which ? grh : glh;
    dst[(hh * NN + j0 + 0) * NHF + f] = a0;
    dst[(hh * NN + j0 + 1) * NHF + f] = a1;
    if (f == 0) {
        float* __restrict__ ab = which ? beta : alpha;
        ab[hh * NN + j0 + 0] = d0;
        ab[hh * NN + j0 + 1] = d1;
    }
}

// K2: one block per (i-tile of 8, head). 512 threads (8 waves), 2 blocks/CU.
// Phase A: e[i,j] = 0.6*(alpha_j + beta_i) + 0.4*sum_f w_f*|gl_jf + gr_if|.
//          gr/beta/w come from block-uniform scalar loads (SGPRs); gl in VGPRs.
// Phase B: softmax over j (wave shfl + LDS combine).
// Phase C: o[ii,f] = sum_j p*g_r; thread <-> (f, j-slice of 64), 8 ii-accs,
//          then LDS partial reduction + ELU + store.
__global__ void __launch_bounds__(512, 4) gat_main(const float* __restrict__ glh,
                                                   const float* __restrict__ grh,
                                                   const float* __restrict__ alpha,
                                                   const float* __restrict__ beta,
                                                   const int* __restrict__ adj,
                                                   const float* __restrict__ attn_w,
                                                   float* __restrict__ out) {
    const int hh  = blockIdx.y;
    const int i0  = blockIdx.x * 8;
    const int tid = threadIdx.x;

    __shared__ float e_buf[8][1028];     // p matrix; stride 1028 keeps rows 16B-aligned
    __shared__ float part[8][16][32];    // Phase C partials [ii][js][f]
    __shared__ float red[8][8];
    __shared__ float m_sh[8], l_sh[8];

    float mpart[8];
#pragma unroll
    for (int ii = 0; ii < 8; ++ii) mpart[ii] = -1e30f;

    // ---- Phase A ----
    for (int c = 0; c < 2; ++c) {
        const int j = (c << 9) + tid;
        const float* __restrict__ gp = glh + (hh * NN + j) * NHF;
        float gl[32];
#pragma unroll
        for (int f4 = 0; f4 < 8; ++f4) {
            const float4 v = *(const float4*)(gp + (f4 << 2));
            gl[f4 * 4 + 0] = v.x; gl[f4 * 4 + 1] = v.y;
            gl[f4 * 4 + 2] = v.z; gl[f4 * 4 + 3] = v.w;
        }
        const float aj = alpha[hh * NN + j];
        int adjv[8];
#pragma unroll
        for (int ii = 0; ii < 8; ++ii) adjv[ii] = adj[(i0 + ii) * NN + j];
#pragma unroll
        for (int ii = 0; ii < 8; ++ii) {
            const float* __restrict__ grp = grh + (hh * NN + i0 + ii) * NHF;  // uniform -> SGPR
            float S0 = 0.f, S1 = 0.f;
#pragma unroll
            for (int f = 0; f < 32; f += 2) {
                const float s0 = gl[f]     + grp[f];
                const float s1 = gl[f + 1] + grp[f + 1];
                S0 = fmaf(fabsf(s0), attn_w[f],     S0);
                S1 = fmaf(fabsf(s1), attn_w[f + 1], S1);
            }
            const float bi = beta[hh * NN + i0 + ii];                          // uniform -> SGPR
            float e = fmaf(0.4f, S0 + S1, 0.6f * (aj + bi));
            e = adjv[ii] ? e : -1e30f;
            e_buf[ii][j] = e;
            mpart[ii] = fmaxf(mpart[ii], e);
        }
    }

    // ---- Phase B: row max ----
    const int lane = tid & 63, wv = tid >> 6;
#pragma unroll
    for (int ii = 0; ii < 8; ++ii) {
        float v = mpart[ii];
#pragma unroll
        for (int d = 32; d > 0; d >>= 1) v = fmaxf(v, __shfl_xor(v, d));
        if (lane == 0) red[ii][wv] = v;
    }
    __syncthreads();
    if (tid < 8) {
        float m = red[tid][0];
#pragma unroll
        for (int w = 1; w < 8; ++w) m = fmaxf(m, red[tid][w]);
        m_sh[tid] = m;
    }
    __syncthreads();

    // exp pass + row sum
    float lpart[8];
#pragma unroll
    for (int ii = 0; ii < 8; ++ii) lpart[ii] = 0.f;
    for (int c = 0; c < 2; ++c) {
        const int j = (c << 9) + tid;
#pragma unroll
        for (int ii = 0; ii < 8; ++ii) {
            const float p = __expf(e_buf[ii][j] - m_sh[ii]);
            e_buf[ii][j] = p;
            lpart[ii] += p;
        }
    }
#pragma unroll
    for (int ii = 0; ii < 8; ++ii) {
        float v = lpart[ii];
#pragma unroll
        for (int d = 32; d > 0; d >>= 1) v += __shfl_xor(v, d);
        if (lane == 0) red[ii][wv] = v;
    }
    __syncthreads();
    if (tid < 8) {
        float l = red[tid][0];
#pragma unroll
        for (int w = 1; w < 8; ++w) l += red[tid][w];
        l_sh[tid] = l;
    }
    __syncthreads();

    // ---- Phase C ----
    const int f  = tid & 31;
    const int js = tid >> 5;            // 16 j-slices of 64
    const float* __restrict__ gp = grh + hh * NN * NHF + f;
    float o[8];
#pragma unroll
    for (int ii = 0; ii < 8; ++ii) o[ii] = 0.f;
    const int jbase = js << 6;
    for (int jj = 0; jj < 64; jj += 4) {
        const int j = jbase + jj;
        const float g0 = gp[(j + 0) * NHF];
        const float g1 = gp[(j + 1) * NHF];
        const float g2 = gp[(j + 2) * NHF];
        const float g3 = gp[(j + 3) * NHF];
#pragma unroll
        for (int ii = 0; ii < 8; ++ii) {
            const float4 p4 = *(const float4*)&e_buf[ii][j];
            o[ii] = fmaf(p4.x, g0, fmaf(p4.y, g1, fmaf(p4.z, g2, fmaf(p4.w, g3, o[ii]))));
        }
    }
#pragma unroll
    for (int ii = 0; ii < 8; ++ii) part[ii][js][f] = o[ii];
    __syncthreads();

    if (tid < 256) {
        const int ii = tid >> 5, ff = tid & 31;
        float s = 0.f;
#pragma unroll
        for (int k = 0; k < 16; ++k) s += part[ii][k][ff];
        s /= l_sh[ii];
        const float r = (s > 0.f) ? s : (__expf(s) - 1.f);
        out[(i0 + ii) * OUT_F + hh * NHF + ff] = r;
    }
}

extern "C" void kernel_launch(void* const* d_in, const int* in_sizes, int n_in,
                              void* d_out, int out_size, void* d_ws, size_t ws_size,
                              hipStream_t stream) {
    const float* hmat = (const float*)d_in[0];
    const int*   adj  = (const int*)d_in[1];
    const float* Wl   = (const float*)d_in[2];
    const float* Wr   = (const float*)d_in[3];
    const float* aw   = (const float*)d_in[4];
    float* o          = (float*)d_out;

    float* glh   = (float*)d_ws;                    // [4][1024][32]
    float* grh   = glh + NHEADS * NN * NHF;         // [4][1024][32]
    float* alpha = grh + NHEADS * NN * NHF;         // [4][1024]
    float* beta  = alpha + NHEADS * NN;             // [4][1024]

    glr_gemm<<<dim3(NN / 2), dim3(256), 0, stream>>>(hmat, Wl, Wr, aw, glh, grh, alpha, beta);
    gat_main<<<dim3(NN / 8, NHEADS), dim3(512), 0, stream>>>(glh, grh, alpha, beta, adj, aw, o);
}

// Round 3
// 100.971 us; speedup vs baseline: 1.2083x; 1.0789x over previous
//
#include <hip/hip_runtime.h>
#include <math.h>

#define NN 1024
#define IN_F 256
#define OUT_F 128
#define NHEADS 4
#define NHF 32
#define HPSTR 260  // LDS h-tile row stride in dwords: 256+4. 260%32==4 -> every
                   // ds_read_b128 across 64 lanes lands exactly 8 dwords/bank (the
                   // b128 floor) -> no bank-conflict penalty.

// K1: g_l = h @ Wl^T, g_r = h @ Wr^T -> [head][row][f] fp32.
// Grid 256 = 16 row-groups x 16 col-sets. Block 256 thr = 4 waves.
// lanes <-> 64 rows (h from LDS, conflict-free); cols wave-uniform via
// readfirstlane -> W reads compile to s_load (scalar pipe). 4 cols/wave.
__global__ void __launch_bounds__(256) glr_gemm(const float* __restrict__ hmat,
                                                const float* __restrict__ Wl,
                                                const float* __restrict__ Wr,
                                                float* __restrict__ glh,
                                                float* __restrict__ grh) {
    __shared__ float hp[64 * HPSTR];  // 66.6 KB
    const int tid = threadIdx.x;
    const int rg = blockIdx.x & 15;   // row-group of 64 rows
    const int cs = blockIdx.x >> 4;   // col-set of 16 cols

    // Stage 64 rows x 256 floats of h, fully coalesced (float4 flat).
    const float4* __restrict__ hsrc = (const float4*)hmat + rg * (64 * 64);
#pragma unroll
    for (int i = 0; i < 16; ++i) {
        const int v = tid + i * 256;          // flat float4 index
        const int row = v >> 6, kq = v & 63;
        const float4 x = hsrc[v];
        *(float4*)(hp + row * HPSTR + kq * 4) = x;
    }
    __syncthreads();

    const int lane = tid & 63;
    const int wu = __builtin_amdgcn_readfirstlane(tid >> 6);  // wave id, provably uniform
    const int c0 = cs * 16 + wu * 4;          // 4 consecutive cols, same W half
    const float* __restrict__ wbase = (c0 < OUT_F) ? (Wl + c0 * IN_F)
                                                   : (Wr + (c0 - OUT_F) * IN_F);
    const float* __restrict__ hrow = hp + lane * HPSTR;

    float a0 = 0.f, a1 = 0.f, a2 = 0.f, a3 = 0.f;
#pragma unroll 4
    for (int kq = 0; kq < 64; ++kq) {
        const float4 hv = *(const float4*)(hrow + kq * 4);
        const float4 w0 = *(const float4*)(wbase + 0 * IN_F + kq * 4);  // s_load
        const float4 w1 = *(const float4*)(wbase + 1 * IN_F + kq * 4);
        const float4 w2 = *(const float4*)(wbase + 2 * IN_F + kq * 4);
        const float4 w3 = *(const float4*)(wbase + 3 * IN_F + kq * 4);
        a0 = fmaf(hv.x, w0.x, fmaf(hv.y, w0.y, fmaf(hv.z, w0.z, fmaf(hv.w, w0.w, a0))));
        a1 = fmaf(hv.x, w1.x, fmaf(hv.y, w1.y, fmaf(hv.z, w1.z, fmaf(hv.w, w1.w, a1))));
        a2 = fmaf(hv.x, w2.x, fmaf(hv.y, w2.y, fmaf(hv.z, w2.z, fmaf(hv.w, w2.w, a2))));
        a3 = fmaf(hv.x, w3.x, fmaf(hv.y, w3.y, fmaf(hv.z, w3.z, fmaf(hv.w, w3.w, a3))));
    }

    const int row = rg * 64 + lane;
    const int cb = c0 & (OUT_F - 1);
    const int hh = cb >> 5;
    const int f  = cb & 31;                   // multiple of 4 -> 16B-aligned store
    float* __restrict__ dst = (c0 < OUT_F) ? glh : grh;
    float4 r; r.x = a0; r.y = a1; r.z = a2; r.w = a3;
    *(float4*)(dst + (hh * NN + row) * NHF + f) = r;
}

// K2: one block per (i-tile of 8, head); 512 thr.
// Phase A fused: e = 0.6*alpha_j + 0.4*sum_f w_f*|gl_jf + gr_if|  (beta_i term
// cancels in softmax and is dropped; e is O(1) so no max pass is needed),
// p = adj ? exp(e) : 0 written to LDS, row-sum accumulated on the fly.
// Phase C: o[ii,f] = sum_j p*g_r, thread <-> (f, j-slice), LDS partial reduce,
// then /l + ELU.
__global__ void __launch_bounds__(512) gat_main(const float* __restrict__ glh,
                                                const float* __restrict__ grh,
                                                const int* __restrict__ adj,
                                                const float* __restrict__ attn_w,
                                                float* __restrict__ out) {
    const int hh  = blockIdx.y;
    const int i0  = blockIdx.x * 8;
    const int tid = threadIdx.x;

    __shared__ float p_buf[8][1028];   // stride%32==4 -> optimal b128 banking
    __shared__ float part[8][16][32];
    __shared__ float red[8][8];
    __shared__ float l_sh[8];

    float lpart[8];
#pragma unroll
    for (int ii = 0; ii < 8; ++ii) lpart[ii] = 0.f;

    // ---- Phase A (e + exp + row-sum fused) ----
    for (int c = 0; c < 2; ++c) {
        const int j = (c << 9) + tid;
        const float* __restrict__ gp = glh + (hh * NN + j) * NHF;
        float gl[NHF];
#pragma unroll
        for (int f4 = 0; f4 < 8; ++f4) {
            const float4 v = *(const float4*)(gp + (f4 << 2));
            gl[4 * f4 + 0] = v.x; gl[4 * f4 + 1] = v.y;
            gl[4 * f4 + 2] = v.z; gl[4 * f4 + 3] = v.w;
        }
        float alpha = 0.f;
#pragma unroll
        for (int f = 0; f < NHF; ++f) alpha = fmaf(gl[f], attn_w[f], alpha);
        int adjv[8];
#pragma unroll
        for (int ii = 0; ii < 8; ++ii) adjv[ii] = adj[(i0 + ii) * NN + j];
#pragma unroll
        for (int ii = 0; ii < 8; ++ii) {
            const float* __restrict__ grp = grh + (hh * NN + i0 + ii) * NHF;  // uniform -> s_load
            float S0 = 0.f, S1 = 0.f;
#pragma unroll
            for (int f = 0; f < NHF; f += 2) {
                const float s0 = gl[f]     + grp[f];
                const float s1 = gl[f + 1] + grp[f + 1];
                S0 = fmaf(fabsf(s0), attn_w[f],     S0);
                S1 = fmaf(fabsf(s1), attn_w[f + 1], S1);
            }
            const float e = fmaf(0.4f, S0 + S1, 0.6f * alpha);
            const float p = adjv[ii] ? __expf(e) : 0.f;
            p_buf[ii][j] = p;
            lpart[ii] += p;
        }
    }

    // ---- row-sum reduction ----
    const int lane = tid & 63, wv = tid >> 6;
#pragma unroll
    for (int ii = 0; ii < 8; ++ii) {
        float v = lpart[ii];
#pragma unroll
        for (int d = 32; d > 0; d >>= 1) v += __shfl_xor(v, d);
        if (lane == 0) red[ii][wv] = v;
    }
    __syncthreads();
    if (tid < 8) {
        float l = red[tid][0];
#pragma unroll
        for (int w = 1; w < 8; ++w) l += red[tid][w];
        l_sh[tid] = l;
    }
    __syncthreads();

    // ---- Phase C ----
    const int f  = tid & 31;
    const int js = tid >> 5;                  // 16 j-slices of 64
    const float* __restrict__ gp = grh + hh * NN * NHF + f;
    float o[8];
#pragma unroll
    for (int ii = 0; ii < 8; ++ii) o[ii] = 0.f;
    const int jb = js << 6;
    for (int jj = 0; jj < 64; jj += 4) {
        const int j = jb + jj;
        const float g0 = gp[(j + 0) * NHF];
        const float g1 = gp[(j + 1) * NHF];
        const float g2 = gp[(j + 2) * NHF];
        const float g3 = gp[(j + 3) * NHF];
#pragma unroll
        for (int ii = 0; ii < 8; ++ii) {
            const float4 p4 = *(const float4*)&p_buf[ii][j];
            o[ii] = fmaf(p4.x, g0, fmaf(p4.y, g1, fmaf(p4.z, g2, fmaf(p4.w, g3, o[ii]))));
        }
    }
#pragma unroll
    for (int ii = 0; ii < 8; ++ii) part[ii][js][f] = o[ii];
    __syncthreads();

    if (tid < 256) {
        const int ii = tid >> 5, ff = tid & 31;
        float s = 0.f;
#pragma unroll
        for (int k = 0; k < 16; ++k) s += part[ii][k][ff];
        s /= l_sh[ii];
        const float r = (s > 0.f) ? s : (__expf(s) - 1.f);
        out[(i0 + ii) * OUT_F + hh * NHF + ff] = r;
    }
}

extern "C" void kernel_launch(void* const* d_in, const int* in_sizes, int n_in,
                              void* d_out, int out_size, void* d_ws, size_t ws_size,
                              hipStream_t stream) {
    const float* hmat = (const float*)d_in[0];
    const int*   adj  = (const int*)d_in[1];
    const float* Wl   = (const float*)d_in[2];
    const float* Wr   = (const float*)d_in[3];
    const float* aw   = (const float*)d_in[4];
    float* o          = (float*)d_out;

    float* glh = (float*)d_ws;                 // [4][1024][32]
    float* grh = glh + NHEADS * NN * NHF;      // [4][1024][32]

    glr_gemm<<<dim3(256), dim3(256), 0, stream>>>(hmat, Wl, Wr, glh, grh);
    gat_main<<<dim3(NN / 8, NHEADS), dim3(512), 0, stream>>>(glh, grh, adj, aw, o);
}